// Round 1
// baseline (181.225 us; speedup 1.0000x reference)
//
#include <hip/hip_runtime.h>
#include <math.h>

#define L_SEQ 16384
#define H_DIM 1024
#define P_DIM 512
#define N2P   1024
#define CHUNK 64
#define NCHUNK 256   // L_SEQ / CHUNK

typedef __attribute__((ext_vector_type(8))) short short8;
typedef __attribute__((ext_vector_type(4))) float f32x4;

__device__ __forceinline__ unsigned short f2bf(float f){
    unsigned int u = __float_as_uint(f);
    u = (u + 0x7FFFu + ((u >> 16) & 1u)) >> 16;
    return (unsigned short)u;
}

// ---------------- prep: lambda_bar, coef=(lambda_bar-1)/Lambda, lambda_bar^CHUNK ---
__global__ void k_prep_lambda(const float* __restrict__ lre, const float* __restrict__ lim,
                              const float* __restrict__ lstep,
                              float* __restrict__ lam, float* __restrict__ coef,
                              float* __restrict__ lpow)
{
    int p = threadIdx.x;
    double step = exp((double)lstep[p]);
    double dr = (double)lre[p], di = (double)lim[p];
    double ar = dr*step, ai = di*step;
    double er = exp(ar);
    double lbr = er*cos(ai), lbi = er*sin(ai);
    lam[2*p] = (float)lbr; lam[2*p+1] = (float)lbi;
    double nr = lbr - 1.0, ni = lbi;
    double d2 = dr*dr + di*di;
    coef[2*p]   = (float)((nr*dr + ni*di)/d2);
    coef[2*p+1] = (float)((ni*dr - nr*di)/d2);
    double xr = lbr, xi = lbi;
    #pragma unroll
    for (int s=0;s<6;s++){ double t = xr*xr - xi*xi; xi = 2.0*xr*xi; xr = t; } // ^64
    lpow[2*p] = (float)xr; lpow[2*p+1] = (float)xi;
}

// BB[(2p)][h] = Re(coef_p * B_tilde[p][h]); BB[(2p+1)][h] = Im(...)   (N=2P, K=H) row-major bf16
__global__ __launch_bounds__(256)
void k_prep_BB(const float* __restrict__ B, const float* __restrict__ coef,
               unsigned short* __restrict__ BB)
{
    int i = blockIdx.x*256 + threadIdx.x;   // i = p*H + h
    int p = i >> 10, h = i & 1023;
    float br = B[2*i], bi = B[2*i+1];
    float cr = coef[2*p], ci = coef[2*p+1];
    BB[(size_t)(2*p)*H_DIM + h]   = f2bf(cr*br - ci*bi);
    BB[(size_t)(2*p+1)*H_DIM + h] = f2bf(cr*bi + ci*br);
}

// CC[h][2p] = 2*Re(C[h][p]); CC[h][2p+1] = -2*Im(C[h][p])   (N=H, K=2P) row-major bf16
__global__ __launch_bounds__(256)
void k_prep_CC(const float* __restrict__ C, unsigned short* __restrict__ CC)
{
    int i = blockIdx.x*256 + threadIdx.x;   // i = h*P + p
    int h = i >> 9, p = i & 511;
    float cr = C[2*i], ci = C[2*i+1];
    CC[(size_t)h*N2P + 2*p]     = f2bf(2.f*cr);
    CC[(size_t)h*N2P + 2*p + 1] = f2bf(-2.f*ci);
}

// fp32 -> bf16 cast of u, 8 elements/thread
__global__ __launch_bounds__(256)
void k_cast(const float4* __restrict__ u, unsigned short* __restrict__ o)
{
    int i = blockIdx.x*256 + threadIdx.x;
    float4 a = u[2*i], b = u[2*i+1];
    union { short8 v; unsigned short s[8]; } r;
    r.s[0]=f2bf(a.x); r.s[1]=f2bf(a.y); r.s[2]=f2bf(a.z); r.s[3]=f2bf(a.w);
    r.s[4]=f2bf(b.x); r.s[5]=f2bf(b.y); r.s[6]=f2bf(b.z); r.s[7]=f2bf(b.w);
    *reinterpret_cast<short8*>(o + (size_t)i*8) = r.v;
}

// ---------------- GEMM: C[M][1024] = A[M][K]bf16 @ Bm[1024][K]bf16^T (+ epilogue) ----
// m97-style: 128x128 tile, BK=32, 4 waves (2x2), global_load_lds w=16, 16x16x32 MFMA
template<int EPI>
__global__ __launch_bounds__(256)
void gemm_bt(const unsigned short* __restrict__ A, const unsigned short* __restrict__ Bm,
             float* __restrict__ Cc, int K, const float* __restrict__ Dv,
             const float* __restrict__ U)
{
    constexpr int NN = 1024;
    __shared__ unsigned short As[128*32];
    __shared__ unsigned short Bs[128*32];
    const int tid = threadIdx.x;
    const int lane = tid & 63;
    const int wid = tid >> 6;
    const int wm = wid >> 1, wn = wid & 1;
    const int tm = blockIdx.x, tn = blockIdx.y;

    const int r0 = tid >> 2;          // staging row (pass0), pass1 = +64
    const int c0 = (tid & 3) * 8;     // staging col chunk
    const unsigned short* Ag0 = A + (size_t)(tm*128 + r0) * K + c0;
    const unsigned short* Ag1 = Ag0 + (size_t)64 * K;
    const unsigned short* Bg0 = Bm + (size_t)(tn*128 + r0) * K + c0;
    const unsigned short* Bg1 = Bg0 + (size_t)64 * K;
    unsigned short* AsW0 = As + wid*512;         // wave-uniform LDS bases
    unsigned short* AsW1 = As + 2048 + wid*512;
    unsigned short* BsW0 = Bs + wid*512;
    unsigned short* BsW1 = Bs + 2048 + wid*512;

    const int lr = lane & 15;
    const int lk = (lane >> 4) * 8;

    f32x4 acc[4][4];
    #pragma unroll
    for (int i=0;i<4;i++)
        #pragma unroll
        for (int j=0;j<4;j++) acc[i][j] = (f32x4){0.f,0.f,0.f,0.f};

    for (int k0 = 0; k0 < K; k0 += 32) {
        __builtin_amdgcn_global_load_lds((const __attribute__((address_space(1))) void*)(Ag0 + k0),
                                         (__attribute__((address_space(3))) void*)AsW0, 16, 0, 0);
        __builtin_amdgcn_global_load_lds((const __attribute__((address_space(1))) void*)(Ag1 + k0),
                                         (__attribute__((address_space(3))) void*)AsW1, 16, 0, 0);
        __builtin_amdgcn_global_load_lds((const __attribute__((address_space(1))) void*)(Bg0 + k0),
                                         (__attribute__((address_space(3))) void*)BsW0, 16, 0, 0);
        __builtin_amdgcn_global_load_lds((const __attribute__((address_space(1))) void*)(Bg1 + k0),
                                         (__attribute__((address_space(3))) void*)BsW1, 16, 0, 0);
        __syncthreads();
        short8 af[4], bf[4];
        #pragma unroll
        for (int m=0;m<4;m++)
            af[m] = *reinterpret_cast<const short8*>(As + (wm*64 + m*16 + lr)*32 + lk);
        #pragma unroll
        for (int n=0;n<4;n++)
            bf[n] = *reinterpret_cast<const short8*>(Bs + (wn*64 + n*16 + lr)*32 + lk);
        #pragma unroll
        for (int m=0;m<4;m++)
            #pragma unroll
            for (int n=0;n<4;n++)
                acc[m][n] = __builtin_amdgcn_mfma_f32_16x16x32_bf16(af[m], bf[n], acc[m][n], 0, 0, 0);
        __syncthreads();
    }

    const int orow = tm*128 + wm*64;
    const int ocol = tn*128 + wn*64;
    #pragma unroll
    for (int m=0;m<4;m++){
        #pragma unroll
        for (int n=0;n<4;n++){
            int rbase = orow + m*16 + (lane>>4)*4;
            int col = ocol + n*16 + lr;
            #pragma unroll
            for (int j=0;j<4;j++){
                size_t idx = (size_t)(rbase + j)*NN + col;
                float v = acc[m][n][j];
                if (EPI) v += Dv[col]*U[idx];
                Cc[idx] = v;
            }
        }
    }
}

// ---------------- scan phase 1: per-(chunk, p) aggregate b_c --------------------
__global__ __launch_bounds__(512)
void k_agg(const float* __restrict__ Bu, const float* __restrict__ lam, float* __restrict__ agg)
{
    int p = threadIdx.x, c = blockIdx.x;
    float lrr = lam[2*p], lii = lam[2*p+1];
    float xr = 0.f, xi = 0.f;
    const float2* b2 = (const float2*)Bu + (size_t)c*CHUNK*512 + p;
    #pragma unroll 4
    for (int t=0;t<CHUNK;t++){
        float2 b = b2[(size_t)t*512];
        float tr = lrr*xr - lii*xi + b.x;
        xi = lrr*xi + lii*xr + b.y;
        xr = tr;
    }
    agg[((size_t)c*P_DIM + p)*2]     = xr;
    agg[((size_t)c*P_DIM + p)*2 + 1] = xi;
}

// ---------------- scan phase 2: Kogge-Stone over chunks, per p (one block per p) --
__global__ __launch_bounds__(256)
void k_scan(const float* __restrict__ agg, const float* __restrict__ lpow,
            float* __restrict__ xinit)
{
    __shared__ float sr[NCHUNK], si[NCHUNK];
    int c = threadIdx.x, p = blockIdx.x;
    float xr = agg[((size_t)c*P_DIM + p)*2];
    float xi = agg[((size_t)c*P_DIM + p)*2 + 1];
    sr[c] = xr; si[c] = xi;
    float wr = lpow[2*p], wi = lpow[2*p+1];
    for (int s=1; s<NCHUNK; s<<=1){
        __syncthreads();
        float ur = 0.f, ui = 0.f;
        if (c >= s){ ur = sr[c-s]; ui = si[c-s]; }
        __syncthreads();
        xr += wr*ur - wi*ui;
        xi += wr*ui + wi*ur;
        sr[c] = xr; si[c] = xi;
        float t = wr*wr - wi*wi; wi = 2.f*wr*wi; wr = t;
    }
    __syncthreads();
    float er = 0.f, ei = 0.f;
    if (c > 0){ er = sr[c-1]; ei = si[c-1]; }
    xinit[((size_t)c*P_DIM + p)*2]     = er;
    xinit[((size_t)c*P_DIM + p)*2 + 1] = ei;
}

// ---------------- scan phase 3: apply + cast to bf16 (interleaved re/im cols) -----
__global__ __launch_bounds__(512)
void k_apply(const float* __restrict__ Bu, const float* __restrict__ lam,
             const float* __restrict__ xinit, unsigned int* __restrict__ xs)
{
    int p = threadIdx.x, c = blockIdx.x;
    float lrr = lam[2*p], lii = lam[2*p+1];
    float xr = xinit[((size_t)c*P_DIM + p)*2];
    float xi = xinit[((size_t)c*P_DIM + p)*2 + 1];
    const float2* b2 = (const float2*)Bu + (size_t)c*CHUNK*512 + p;
    unsigned int* o = xs + (size_t)c*CHUNK*512 + p;
    #pragma unroll 4
    for (int t=0;t<CHUNK;t++){
        float2 b = b2[(size_t)t*512];
        float tr = lrr*xr - lii*xi + b.x;
        xi = lrr*xi + lii*xr + b.y;
        xr = tr;
        o[(size_t)t*512] = (unsigned int)f2bf(xr) | ((unsigned int)f2bf(xi) << 16);
    }
}

extern "C" void kernel_launch(void* const* d_in, const int* in_sizes, int n_in,
                              void* d_out, int out_size, void* d_ws, size_t ws_size,
                              hipStream_t stream)
{
    const float* u   = (const float*)d_in[0];
    const float* lre = (const float*)d_in[1];
    const float* lim = (const float*)d_in[2];
    const float* B   = (const float*)d_in[3];
    const float* C   = (const float*)d_in[4];
    const float* D   = (const float*)d_in[5];
    const float* ls  = (const float*)d_in[6];
    float* out = (float*)d_out;   // also used as fp32 Bu scratch (exactly L*2P floats)

    char* w = (char*)d_ws;
    unsigned short* u16  = (unsigned short*)(w + 0);          // 32 MiB
    unsigned short* xs16 = (unsigned short*)(w + 33554432);   // 32 MiB
    unsigned short* BB   = (unsigned short*)(w + 67108864);   // 2 MiB
    unsigned short* CC   = (unsigned short*)(w + 69206016);   // 2 MiB
    float* lam   = (float*)(w + 71303168);
    float* coef  = (float*)(w + 71307264);
    float* lpow  = (float*)(w + 71311360);
    float* agg   = (float*)(w + 71315456);                    // 1 MiB
    float* xinit = (float*)(w + 72364032);                    // 1 MiB

    k_prep_lambda<<<1, P_DIM, 0, stream>>>(lre, lim, ls, lam, coef, lpow);
    k_prep_BB<<<(P_DIM*H_DIM)/256, 256, 0, stream>>>(B, coef, BB);
    k_prep_CC<<<(H_DIM*P_DIM)/256, 256, 0, stream>>>(C, CC);
    k_cast<<<(L_SEQ*H_DIM)/(256*8), 256, 0, stream>>>((const float4*)u, u16);

    dim3 g1(L_SEQ/128, N2P/128);
    gemm_bt<0><<<g1, 256, 0, stream>>>(u16, BB, out, H_DIM, nullptr, nullptr);

    k_agg<<<NCHUNK, P_DIM, 0, stream>>>(out, lam, agg);
    k_scan<<<P_DIM, NCHUNK, 0, stream>>>(agg, lpow, xinit);
    k_apply<<<NCHUNK, P_DIM, 0, stream>>>(out, lam, xinit, (unsigned int*)xs16);

    dim3 g2(L_SEQ/128, H_DIM/128);
    gemm_bt<1><<<g2, 256, 0, stream>>>(xs16, CC, out, N2P, D, u);
}

// Round 2
// 147.847 us; speedup vs baseline: 1.2258x; 1.2258x over previous
//
#include <hip/hip_runtime.h>
#include <math.h>

#define L_SEQ 16384
#define H_DIM 1024
#define P_DIM 512
#define N2P   1024
#define KDIM  1024
#define NTILE 16     // KDIM / 64
#define CHUNK 64
#define NCHUNK 256   // L_SEQ / CHUNK

typedef __attribute__((ext_vector_type(8))) short short8;
typedef __attribute__((ext_vector_type(4))) float f32x4;

__device__ __forceinline__ unsigned short f2bf(float f){
    unsigned int u = __float_as_uint(f);
    u = (u + 0x7FFFu + ((u >> 16) & 1u)) >> 16;
    return (unsigned short)u;
}

// ---------------- prep: lambda_bar, coef=(lambda_bar-1)/Lambda, lambda_bar^CHUNK ---
__global__ void k_prep_lambda(const float* __restrict__ lre, const float* __restrict__ lim,
                              const float* __restrict__ lstep,
                              float* __restrict__ lam, float* __restrict__ coef,
                              float* __restrict__ lpow)
{
    int p = threadIdx.x;
    double step = exp((double)lstep[p]);
    double dr = (double)lre[p], di = (double)lim[p];
    double ar = dr*step, ai = di*step;
    double er = exp(ar);
    double lbr = er*cos(ai), lbi = er*sin(ai);
    lam[2*p] = (float)lbr; lam[2*p+1] = (float)lbi;
    double nr = lbr - 1.0, ni = lbi;
    double d2 = dr*dr + di*di;
    coef[2*p]   = (float)((nr*dr + ni*di)/d2);
    coef[2*p+1] = (float)((ni*dr - nr*di)/d2);
    double xr = lbr, xi = lbi;
    #pragma unroll
    for (int s=0;s<6;s++){ double t = xr*xr - xi*xi; xi = 2.0*xr*xi; xr = t; } // ^64
    lpow[2*p] = (float)xr; lpow[2*p+1] = (float)xi;
}

__global__ __launch_bounds__(256)
void k_prep_BB(const float* __restrict__ B, const float* __restrict__ coef,
               unsigned short* __restrict__ BB)
{
    int i = blockIdx.x*256 + threadIdx.x;   // i = p*H + h
    int p = i >> 10, h = i & 1023;
    float br = B[2*i], bi = B[2*i+1];
    float cr = coef[2*p], ci = coef[2*p+1];
    BB[(size_t)(2*p)*H_DIM + h]   = f2bf(cr*br - ci*bi);
    BB[(size_t)(2*p+1)*H_DIM + h] = f2bf(cr*bi + ci*br);
}

__global__ __launch_bounds__(256)
void k_prep_CC(const float* __restrict__ C, unsigned short* __restrict__ CC)
{
    int i = blockIdx.x*256 + threadIdx.x;   // i = h*P + p
    int h = i >> 9, p = i & 511;
    float cr = C[2*i], ci = C[2*i+1];
    CC[(size_t)h*N2P + 2*p]     = f2bf(2.f*cr);
    CC[(size_t)h*N2P + 2*p + 1] = f2bf(-2.f*ci);
}

__global__ __launch_bounds__(256)
void k_cast(const float4* __restrict__ u, unsigned short* __restrict__ o)
{
    int i = blockIdx.x*256 + threadIdx.x;
    float4 a = u[2*i], b = u[2*i+1];
    union { short8 v; unsigned short s[8]; } r;
    r.s[0]=f2bf(a.x); r.s[1]=f2bf(a.y); r.s[2]=f2bf(a.z); r.s[3]=f2bf(a.w);
    r.s[4]=f2bf(b.x); r.s[5]=f2bf(b.y); r.s[6]=f2bf(b.z); r.s[7]=f2bf(b.w);
    *reinterpret_cast<short8*>(o + (size_t)i*8) = r.v;
}

// ---------------- GEMM: 256x256 tile, BK=64, 8 waves (2x4), 8-phase counted-vmcnt ----
// C[M][1024] = A[M][1024]bf16 @ Bm[1024][1024]bf16^T (+ optional D*U epilogue)
// LDS per dbuf slot (64KB): A 256x64 as [g:2][idx:128][col:64], B same at +32KB.
//   A group g holds tile rows {g*64..g*64+63} U {128+g*64..}; idx=(r>>7)*64|(r&63)
//   B group g holds tile rows with bit5==g;                    idx=(r>>6)*32|(r&31)
// XOR swizzle (T2): physical colbyte = logical ^ ((idx&7)<<4); applied via
// pre-swizzled global source (linear gload dest) + swizzled ds_read (rule #21).
template<int EPI>
__global__ __launch_bounds__(512, 2)
void gemm256(const unsigned short* __restrict__ A, const unsigned short* __restrict__ Bm,
             float* __restrict__ Cc, const float* __restrict__ Dv, const float* __restrict__ U)
{
    __shared__ char lds[131072];
    const int tid  = threadIdx.x;
    const int lane = tid & 63;
    const int wid  = tid >> 6;
    const int wm = wid >> 2, wn = wid & 3;          // 2(M) x 4(N) waves
    const int wg = ((int)blockIdx.x & 7) * 32 + ((int)blockIdx.x >> 3);  // XCD swizzle (256%8==0)
    const int tm = wg >> 2, tn = wg & 3;

    const int lr = lane & 15;
    const int l8 = lane >> 3;
    const int i0 = wid * 8 + l8;                    // staging LDS row idx (0..63), +64 for 2nd gload
    const int scol = ((lane & 7) * 8) ^ ((l8 & 7) << 3);            // ushort units, pre-swizzled src col
    const int kc0 = ( (lane >> 4) * 16      ) ^ ((lr & 7) << 4);    // bytes, swizzled read col ksub0
    const int kc1 = ( (lane >> 4) * 16 + 64 ) ^ ((lr & 7) << 4);    // ksub1
    const int aBase = wm * 8192 + lr * 128;                         // + g*16384 + (fm&3)*2048
    const int bBase = 32768 + wn * 4096 + lr * 128;                 // + (fn>>1)*16384 + (fn&1)*2048
    const int ldsW = wid * 1024;                                    // wave-uniform stage dest

    const size_t arow0 = (size_t)(tm*256 + i0) * KDIM + scol;
    const int rb0 = ((i0 >> 5) << 6) | (i0 & 31);
    const size_t brow0 = (size_t)(tn*256 + rb0) * KDIM + scol;

#define GLOAD(SRC, DST) __builtin_amdgcn_global_load_lds( \
        (const __attribute__((address_space(1))) void*)(SRC), \
        (__attribute__((address_space(3))) void*)(DST), 16, 0, 0)
#define STAGE_A(g, tt, sbN) do{ \
    const unsigned short* s_ = A + arow0 + (size_t)(g)*64*KDIM + (size_t)(tt)*64; \
    GLOAD(s_,                    lds + (sbN) + (g)*16384 + ldsW); \
    GLOAD(s_ + (size_t)128*KDIM, lds + (sbN) + (g)*16384 + 8192 + ldsW); \
  }while(0)
#define STAGE_B(g, tt, sbN) do{ \
    const unsigned short* s_ = Bm + brow0 + (size_t)(g)*32*KDIM + (size_t)(tt)*64; \
    GLOAD(s_,                    lds + (sbN) + 32768 + (g)*16384 + ldsW); \
    GLOAD(s_ + (size_t)128*KDIM, lds + (sbN) + 32768 + (g)*16384 + 8192 + ldsW); \
  }while(0)
#define RD(OFF) (*(const short8*)(lds + (OFF)))
#define MFMA(a,b,c) __builtin_amdgcn_mfma_f32_16x16x32_bf16(a,b,c,0,0,0)
#define VMW6 asm volatile("s_waitcnt vmcnt(6)" ::: "memory")
#define BAR __builtin_amdgcn_s_barrier()

    short8 af[4][2], b0[2][2], b1[2][2];
    f32x4 acc[8][4];
    #pragma unroll
    for (int m=0;m<8;m++)
        #pragma unroll
        for (int n=0;n<4;n++) acc[m][n] = (f32x4){0.f,0.f,0.f,0.f};

    // prologue: tile 0, issue order must match steady state [Ag0,Bg0,Bg1,Ag1]
    STAGE_A(0, 0, 0); STAGE_B(0, 0, 0); STAGE_B(1, 0, 0); STAGE_A(1, 0, 0);

    for (int t = 0; t < NTILE; ++t) {
        const int sb  = (t & 1) << 16;
        const int sbN = sb ^ 65536;
        const int tt  = (t+1 < NTILE) ? t+1 : t;   // last-tile dummy prefetch keeps vmcnt math uniform
        // ---- P1: quadrant (fm 0-3, fn 0-1); consumes Ag0(t), Bg0(t)
        STAGE_A(0, tt, sbN);
        VMW6; BAR;
        #pragma unroll
        for (int m=0;m<4;m++){ af[m][0]=RD(sb+aBase+m*2048+kc0); af[m][1]=RD(sb+aBase+m*2048+kc1); }
        #pragma unroll
        for (int n=0;n<2;n++){ b0[n][0]=RD(sb+bBase+n*2048+kc0); b0[n][1]=RD(sb+bBase+n*2048+kc1); }
        __builtin_amdgcn_s_setprio(1);
        #pragma unroll
        for (int m=0;m<4;m++)
            #pragma unroll
            for (int n=0;n<2;n++){
                acc[m][n]=MFMA(af[m][0],b0[n][0],acc[m][n]);
                acc[m][n]=MFMA(af[m][1],b0[n][1],acc[m][n]); }
        __builtin_amdgcn_s_setprio(0); BAR;
        // ---- P2: (fm 0-3, fn 2-3); consumes Bg1(t)
        STAGE_B(0, tt, sbN);
        VMW6; BAR;
        #pragma unroll
        for (int n=0;n<2;n++){ b1[n][0]=RD(sb+bBase+16384+n*2048+kc0); b1[n][1]=RD(sb+bBase+16384+n*2048+kc1); }
        __builtin_amdgcn_s_setprio(1);
        #pragma unroll
        for (int m=0;m<4;m++)
            #pragma unroll
            for (int n=0;n<2;n++){
                acc[m][2+n]=MFMA(af[m][0],b1[n][0],acc[m][2+n]);
                acc[m][2+n]=MFMA(af[m][1],b1[n][1],acc[m][2+n]); }
        __builtin_amdgcn_s_setprio(0); BAR;
        // ---- P3: (fm 4-7, fn 0-1); consumes Ag1(t); b0 regs reused
        STAGE_B(1, tt, sbN);
        VMW6; BAR;
        #pragma unroll
        for (int m=0;m<4;m++){ af[m][0]=RD(sb+16384+aBase+m*2048+kc0); af[m][1]=RD(sb+16384+aBase+m*2048+kc1); }
        __builtin_amdgcn_s_setprio(1);
        #pragma unroll
        for (int m=0;m<4;m++)
            #pragma unroll
            for (int n=0;n<2;n++){
                acc[4+m][n]=MFMA(af[m][0],b0[n][0],acc[4+m][n]);
                acc[4+m][n]=MFMA(af[m][1],b0[n][1],acc[4+m][n]); }
        __builtin_amdgcn_s_setprio(0); BAR;
        // ---- P4: (fm 4-7, fn 2-3); register-only (af from P3, b1 from P2)
        STAGE_A(1, tt, sbN);
        BAR;
        __builtin_amdgcn_s_setprio(1);
        #pragma unroll
        for (int m=0;m<4;m++)
            #pragma unroll
            for (int n=0;n<2;n++){
                acc[4+m][2+n]=MFMA(af[m][0],b1[n][0],acc[4+m][2+n]);
                acc[4+m][2+n]=MFMA(af[m][1],b1[n][1],acc[4+m][2+n]); }
        __builtin_amdgcn_s_setprio(0); BAR;
    }
    asm volatile("s_waitcnt vmcnt(0)" ::: "memory");  // drain dummy prefetch before wave exit

    const int orow0 = tm*256 + wm*128 + (lane>>4)*4;
    const int ocol0 = tn*256 + wn*64 + lr;
    #pragma unroll
    for (int m=0;m<8;m++){
        #pragma unroll
        for (int n=0;n<4;n++){
            int row = orow0 + m*16, col = ocol0 + n*16;
            #pragma unroll
            for (int j=0;j<4;j++){
                size_t idx = (size_t)(row + j)*N2P + col;
                float v = acc[m][n][j];
                if (EPI) v += Dv[col]*U[idx];
                Cc[idx] = v;
            }
        }
    }
#undef GLOAD
#undef STAGE_A
#undef STAGE_B
#undef RD
#undef MFMA
#undef VMW6
#undef BAR
}

// ---------------- scan phase 1: per-(chunk, p) aggregate --------------------
__global__ __launch_bounds__(512)
void k_agg(const float* __restrict__ Bu, const float* __restrict__ lam, float* __restrict__ agg)
{
    int p = threadIdx.x, c = blockIdx.x;
    float lrr = lam[2*p], lii = lam[2*p+1];
    float xr = 0.f, xi = 0.f;
    const float2* b2 = (const float2*)Bu + (size_t)c*CHUNK*512 + p;
    #pragma unroll 4
    for (int t=0;t<CHUNK;t++){
        float2 b = b2[(size_t)t*512];
        float tr = lrr*xr - lii*xi + b.x;
        xi = lrr*xi + lii*xr + b.y;
        xr = tr;
    }
    agg[((size_t)c*P_DIM + p)*2]     = xr;
    agg[((size_t)c*P_DIM + p)*2 + 1] = xi;
}

// ---------------- scan phase 2: Kogge-Stone over chunks ---------------------
__global__ __launch_bounds__(256)
void k_scan(const float* __restrict__ agg, const float* __restrict__ lpow,
            float* __restrict__ xinit)
{
    __shared__ float sr[NCHUNK], si[NCHUNK];
    int c = threadIdx.x, p = blockIdx.x;
    float xr = agg[((size_t)c*P_DIM + p)*2];
    float xi = agg[((size_t)c*P_DIM + p)*2 + 1];
    sr[c] = xr; si[c] = xi;
    float wr = lpow[2*p], wi = lpow[2*p+1];
    for (int s=1; s<NCHUNK; s<<=1){
        __syncthreads();
        float ur = 0.f, ui = 0.f;
        if (c >= s){ ur = sr[c-s]; ui = si[c-s]; }
        __syncthreads();
        xr += wr*ur - wi*ui;
        xi += wr*ui + wi*ur;
        sr[c] = xr; si[c] = xi;
        float t = wr*wr - wi*wi; wi = 2.f*wr*wi; wr = t;
    }
    __syncthreads();
    float er = 0.f, ei = 0.f;
    if (c > 0){ er = sr[c-1]; ei = si[c-1]; }
    xinit[((size_t)c*P_DIM + p)*2]     = er;
    xinit[((size_t)c*P_DIM + p)*2 + 1] = ei;
}

// ---------------- scan phase 3: apply + cast to bf16 ------------------------
__global__ __launch_bounds__(512)
void k_apply(const float* __restrict__ Bu, const float* __restrict__ lam,
             const float* __restrict__ xinit, unsigned int* __restrict__ xs)
{
    int p = threadIdx.x, c = blockIdx.x;
    float lrr = lam[2*p], lii = lam[2*p+1];
    float xr = xinit[((size_t)c*P_DIM + p)*2];
    float xi = xinit[((size_t)c*P_DIM + p)*2 + 1];
    const float2* b2 = (const float2*)Bu + (size_t)c*CHUNK*512 + p;
    unsigned int* o = xs + (size_t)c*CHUNK*512 + p;
    #pragma unroll 4
    for (int t=0;t<CHUNK;t++){
        float2 b = b2[(size_t)t*512];
        float tr = lrr*xr - lii*xi + b.x;
        xi = lrr*xi + lii*xr + b.y;
        xr = tr;
        o[(size_t)t*512] = (unsigned int)f2bf(xr) | ((unsigned int)f2bf(xi) << 16);
    }
}

extern "C" void kernel_launch(void* const* d_in, const int* in_sizes, int n_in,
                              void* d_out, int out_size, void* d_ws, size_t ws_size,
                              hipStream_t stream)
{
    const float* u   = (const float*)d_in[0];
    const float* lre = (const float*)d_in[1];
    const float* lim = (const float*)d_in[2];
    const float* B   = (const float*)d_in[3];
    const float* C   = (const float*)d_in[4];
    const float* D   = (const float*)d_in[5];
    const float* ls  = (const float*)d_in[6];
    float* out = (float*)d_out;   // fp32 Bu scratch (exactly L*2P floats), then final ys

    char* w = (char*)d_ws;
    unsigned short* u16  = (unsigned short*)(w + 0);          // 32 MiB
    unsigned short* xs16 = (unsigned short*)(w + 33554432);   // 32 MiB
    unsigned short* BB   = (unsigned short*)(w + 67108864);   // 2 MiB
    unsigned short* CC   = (unsigned short*)(w + 69206016);   // 2 MiB
    float* lam   = (float*)(w + 71303168);
    float* coef  = (float*)(w + 71307264);
    float* lpow  = (float*)(w + 71311360);
    float* agg   = (float*)(w + 71315456);                    // 1 MiB
    float* xinit = (float*)(w + 72364032);                    // 1 MiB

    k_prep_lambda<<<1, P_DIM, 0, stream>>>(lre, lim, ls, lam, coef, lpow);
    k_prep_BB<<<(P_DIM*H_DIM)/256, 256, 0, stream>>>(B, coef, BB);
    k_prep_CC<<<(H_DIM*P_DIM)/256, 256, 0, stream>>>(C, CC);
    k_cast<<<(L_SEQ*H_DIM)/(256*8), 256, 0, stream>>>((const float4*)u, u16);

    gemm256<0><<<256, 512, 0, stream>>>(u16, BB, out, nullptr, nullptr);

    k_agg<<<NCHUNK, P_DIM, 0, stream>>>(out, lam, agg);
    k_scan<<<P_DIM, NCHUNK, 0, stream>>>(agg, lpow, xinit);
    k_apply<<<NCHUNK, P_DIM, 0, stream>>>(out, lam, xinit, (unsigned int*)xs16);

    gemm256<1><<<256, 512, 0, stream>>>(xs16, CC, out, D, u);
}

// Round 3
// 135.854 us; speedup vs baseline: 1.3340x; 1.0883x over previous
//
#include <hip/hip_runtime.h>
#include <math.h>

#define L_SEQ 16384
#define H_DIM 1024
#define P_DIM 512
#define N2P   1024
#define KDIM  1024
#define NTILE 32     // KDIM / 32
#define CHUNK 64
#define NCHUNK 256   // L_SEQ / CHUNK

typedef __attribute__((ext_vector_type(8))) short short8;
typedef __attribute__((ext_vector_type(4))) float f32x4;

__device__ __forceinline__ unsigned short f2bf(float f){
    unsigned int u = __float_as_uint(f);
    u = (u + 0x7FFFu + ((u >> 16) & 1u)) >> 16;
    return (unsigned short)u;
}
__device__ __forceinline__ float bf2f(unsigned int lo16){
    return __uint_as_float(lo16 << 16);
}

// ---------------- prep ----------------
__global__ void k_prep_lambda(const float* __restrict__ lre, const float* __restrict__ lim,
                              const float* __restrict__ lstep,
                              float* __restrict__ lam, float* __restrict__ coef,
                              float* __restrict__ lpow)
{
    int p = threadIdx.x;
    double step = exp((double)lstep[p]);
    double dr = (double)lre[p], di = (double)lim[p];
    double ar = dr*step, ai = di*step;
    double er = exp(ar);
    double lbr = er*cos(ai), lbi = er*sin(ai);
    lam[2*p] = (float)lbr; lam[2*p+1] = (float)lbi;
    double nr = lbr - 1.0, ni = lbi;
    double d2 = dr*dr + di*di;
    coef[2*p]   = (float)((nr*dr + ni*di)/d2);
    coef[2*p+1] = (float)((ni*dr - nr*di)/d2);
    double xr = lbr, xi = lbi;
    #pragma unroll
    for (int s=0;s<6;s++){ double t = xr*xr - xi*xi; xi = 2.0*xr*xi; xr = t; } // ^64
    lpow[2*p] = (float)xr; lpow[2*p+1] = (float)xi;
}

__global__ __launch_bounds__(256)
void k_prep_BB(const float* __restrict__ B, const float* __restrict__ coef,
               unsigned short* __restrict__ BB)
{
    int i = blockIdx.x*256 + threadIdx.x;   // i = p*H + h
    int p = i >> 10, h = i & 1023;
    float br = B[2*i], bi = B[2*i+1];
    float cr = coef[2*p], ci = coef[2*p+1];
    BB[(size_t)(2*p)*H_DIM + h]   = f2bf(cr*br - ci*bi);
    BB[(size_t)(2*p+1)*H_DIM + h] = f2bf(cr*bi + ci*br);
}

__global__ __launch_bounds__(256)
void k_prep_CC(const float* __restrict__ C, unsigned short* __restrict__ CC)
{
    int i = blockIdx.x*256 + threadIdx.x;   // i = h*P + p
    int h = i >> 9, p = i & 511;
    float cr = C[2*i], ci = C[2*i+1];
    CC[(size_t)h*N2P + 2*p]     = f2bf(2.f*cr);
    CC[(size_t)h*N2P + 2*p + 1] = f2bf(-2.f*ci);
}

__global__ __launch_bounds__(256)
void k_cast(const float4* __restrict__ u, unsigned short* __restrict__ o)
{
    int i = blockIdx.x*256 + threadIdx.x;
    float4 a = u[2*i], b = u[2*i+1];
    union { short8 v; unsigned short s[8]; } r;
    r.s[0]=f2bf(a.x); r.s[1]=f2bf(a.y); r.s[2]=f2bf(a.z); r.s[3]=f2bf(a.w);
    r.s[4]=f2bf(b.x); r.s[5]=f2bf(b.y); r.s[6]=f2bf(b.z); r.s[7]=f2bf(b.w);
    *reinterpret_cast<short8*>(o + (size_t)i*8) = r.v;
}

// ---------------- GEMM: 256x256 tile, BK=32, 4 LDS buffers, 3-tile prefetch -------
// C[M][1024] = A[M][1024]bf16 @ Bm[1024][1024]bf16^T
// EPI=0: store bf16 to Cb. EPI=1: store f32 to Cf with += Dv[col]*bf16(U16).
// LDS: A bufs [4][256][32]bf16 at b*16384; B bufs at 65536 + b*16384.
// Swizzle: chunk16B physical = logical ^ (row&3); linear gload dest + pre-swizzled
// global source + swizzled ds_read (both-sides rule #21).
// Per K-tile, 2 phases: Ph1 {STAGE_A(t+3); vmcnt(10); BAR; read af x8 + b01; MFMA x16}
//                       Ph2 {STAGE_B(t+3); BAR; read b23; MFMA x16}
template<int EPI>
__global__ __launch_bounds__(512, 2)
void gemm256(const unsigned short* __restrict__ A, const unsigned short* __restrict__ Bm,
             float* __restrict__ Cf, unsigned short* __restrict__ Cb,
             const float* __restrict__ Dv, const unsigned short* __restrict__ U16)
{
    __shared__ char lds[131072];
    const int tid  = threadIdx.x;
    const int lane = tid & 63;
    const int wid  = tid >> 6;
    const int wm = wid >> 2, wn = wid & 3;          // 2(M) x 4(N) waves
    const int wg = ((int)blockIdx.x & 7) * 32 + ((int)blockIdx.x >> 3);  // XCD swizzle
    const int tm = wg >> 2, tn = wg & 3;
    const int lr = lane & 15;

    // staging: 512 threads cover 128 rows x 64B; two gloads per operand (rows +0,+128)
    const int srow = wid*16 + (lane >> 2);                     // 0..127
    const int scol = (((lane & 3) ^ ((lane >> 2) & 3)) << 3);  // ushort units, pre-swizzled
    const size_t aS0 = (size_t)(tm*256 + srow) * KDIM + scol;
    const size_t bS0 = (size_t)(tn*256 + srow) * KDIM + scol;
    const int ldsW = wid * 1024;

    // reading: fragment at row R: byte = R*64 + ((lane>>4)^(R&3))*16, R&3 == lr&3
    const int kc   = (((lane >> 4) << 4) ^ ((lr & 3) << 4));
    const int aOff = (wm*128 + lr)*64 + kc;          // + m*1024
    const int bOff = 65536 + (wn*64 + lr)*64 + kc;   // + n*1024

#define GLOAD(SRC, DST) __builtin_amdgcn_global_load_lds( \
        (const __attribute__((address_space(1))) void*)(SRC), \
        (__attribute__((address_space(3))) void*)(DST), 16, 0, 0)
#define STAGE_A(tt) do{ int bb_ = ((tt)&3)*16384; \
    const unsigned short* s_ = A + aS0 + (size_t)(tt)*32; \
    GLOAD(s_,                    lds + bb_ + ldsW); \
    GLOAD(s_ + (size_t)128*KDIM, lds + bb_ + 8192 + ldsW); }while(0)
#define STAGE_B(tt) do{ int bb_ = 65536 + ((tt)&3)*16384; \
    const unsigned short* s_ = Bm + bS0 + (size_t)(tt)*32; \
    GLOAD(s_,                    lds + bb_ + ldsW); \
    GLOAD(s_ + (size_t)128*KDIM, lds + bb_ + 8192 + ldsW); }while(0)
#define RD(OFF) (*(const short8*)(lds + (OFF)))
#define MFMA(a,b,c) __builtin_amdgcn_mfma_f32_16x16x32_bf16(a,b,c,0,0,0)
#define BAR __builtin_amdgcn_s_barrier()

    short8 af[8], bfr[4];
    f32x4 acc[8][4];
    #pragma unroll
    for (int m=0;m<8;m++)
        #pragma unroll
        for (int n=0;n<4;n++) acc[m][n] = (f32x4){0.f,0.f,0.f,0.f};

    // prologue: 3 tiles deep, FIFO order [A,A,B,B] per tile
    STAGE_A(0); STAGE_B(0); STAGE_A(1); STAGE_B(1); STAGE_A(2); STAGE_B(2);

    for (int t = 0; t < NTILE; ++t) {
        const int sb = (t & 3) * 16384;
        const int tt = (t+3 < NTILE) ? t+3 : NTILE-1;  // dummy re-stage at tail keeps vmcnt uniform
        // ---- Ph1: consumes A(t) fully + B(t) rows fn0-1
        STAGE_A(tt);
        asm volatile("s_waitcnt vmcnt(10)" ::: "memory");
        BAR;
        #pragma unroll
        for (int m=0;m<8;m++) af[m] = RD(sb + aOff + m*1024);
        bfr[0] = RD(sb + bOff);
        bfr[1] = RD(sb + bOff + 1024);
        __builtin_amdgcn_s_setprio(1);
        #pragma unroll
        for (int m=0;m<8;m++){
            acc[m][0] = MFMA(af[m], bfr[0], acc[m][0]);
            acc[m][1] = MFMA(af[m], bfr[1], acc[m][1]);
        }
        __builtin_amdgcn_s_setprio(0);
        // ---- Ph2: consumes B(t) rows fn2-3 (already drained at Ph1's vmcnt)
        STAGE_B(tt);
        BAR;
        bfr[2] = RD(sb + bOff + 2048);
        bfr[3] = RD(sb + bOff + 3072);
        __builtin_amdgcn_s_setprio(1);
        #pragma unroll
        for (int m=0;m<8;m++){
            acc[m][2] = MFMA(af[m], bfr[2], acc[m][2]);
            acc[m][3] = MFMA(af[m], bfr[3], acc[m][3]);
        }
        __builtin_amdgcn_s_setprio(0);
    }
    asm volatile("s_waitcnt vmcnt(0)" ::: "memory");  // drain tail dummy prefetches

    const int orow0 = tm*256 + wm*128 + (lane>>4)*4;
    const int ocol0 = tn*256 + wn*64 + lr;
    #pragma unroll
    for (int m=0;m<8;m++){
        #pragma unroll
        for (int n=0;n<4;n++){
            int row = orow0 + m*16, col = ocol0 + n*16;
            #pragma unroll
            for (int j=0;j<4;j++){
                size_t idx = (size_t)(row + j)*N2P + col;
                if (EPI) Cf[idx] = acc[m][n][j] + Dv[col]*bf2f(U16[idx]);
                else     Cb[idx] = f2bf(acc[m][n][j]);
            }
        }
    }
#undef GLOAD
#undef STAGE_A
#undef STAGE_B
#undef RD
#undef MFMA
#undef BAR
}

// ---------------- scan phase 1: per-(chunk, p) aggregate (Bu in bf16 pairs) -------
__global__ __launch_bounds__(512)
void k_agg(const unsigned int* __restrict__ Bu, const float* __restrict__ lam,
           float* __restrict__ agg)
{
    int p = threadIdx.x, c = blockIdx.x;
    float lrr = lam[2*p], lii = lam[2*p+1];
    float xr = 0.f, xi = 0.f;
    const unsigned int* b2 = Bu + (size_t)c*CHUNK*512 + p;
    #pragma unroll 4
    for (int t=0;t<CHUNK;t++){
        unsigned int b = b2[(size_t)t*512];
        float br = __uint_as_float(b << 16);
        float bi = __uint_as_float(b & 0xffff0000u);
        float tr = lrr*xr - lii*xi + br;
        xi = lrr*xi + lii*xr + bi;
        xr = tr;
    }
    agg[((size_t)c*P_DIM + p)*2]     = xr;
    agg[((size_t)c*P_DIM + p)*2 + 1] = xi;
}

// ---------------- scan phase 2: Kogge-Stone over chunks ---------------------
__global__ __launch_bounds__(256)
void k_scan(const float* __restrict__ agg, const float* __restrict__ lpow,
            float* __restrict__ xinit)
{
    __shared__ float sr[NCHUNK], si[NCHUNK];
    int c = threadIdx.x, p = blockIdx.x;
    float xr = agg[((size_t)c*P_DIM + p)*2];
    float xi = agg[((size_t)c*P_DIM + p)*2 + 1];
    sr[c] = xr; si[c] = xi;
    float wr = lpow[2*p], wi = lpow[2*p+1];
    for (int s=1; s<NCHUNK; s<<=1){
        __syncthreads();
        float ur = 0.f, ui = 0.f;
        if (c >= s){ ur = sr[c-s]; ui = si[c-s]; }
        __syncthreads();
        xr += wr*ur - wi*ui;
        xi += wr*ui + wi*ur;
        sr[c] = xr; si[c] = xi;
        float t = wr*wr - wi*wi; wi = 2.f*wr*wi; wr = t;
    }
    __syncthreads();
    float er = 0.f, ei = 0.f;
    if (c > 0){ er = sr[c-1]; ei = si[c-1]; }
    xinit[((size_t)c*P_DIM + p)*2]     = er;
    xinit[((size_t)c*P_DIM + p)*2 + 1] = ei;
}

// ---------------- scan phase 3: apply + emit bf16 pairs ----------------------
__global__ __launch_bounds__(512)
void k_apply(const unsigned int* __restrict__ Bu, const float* __restrict__ lam,
             const float* __restrict__ xinit, unsigned int* __restrict__ xs)
{
    int p = threadIdx.x, c = blockIdx.x;
    float lrr = lam[2*p], lii = lam[2*p+1];
    float xr = xinit[((size_t)c*P_DIM + p)*2];
    float xi = xinit[((size_t)c*P_DIM + p)*2 + 1];
    const unsigned int* b2 = Bu + (size_t)c*CHUNK*512 + p;
    unsigned int* o = xs + (size_t)c*CHUNK*512 + p;
    #pragma unroll 4
    for (int t=0;t<CHUNK;t++){
        unsigned int b = b2[(size_t)t*512];
        float br = __uint_as_float(b << 16);
        float bi = __uint_as_float(b & 0xffff0000u);
        float tr = lrr*xr - lii*xi + br;
        xi = lrr*xi + lii*xr + bi;
        xr = tr;
        o[(size_t)t*512] = (unsigned int)f2bf(xr) | ((unsigned int)f2bf(xi) << 16);
    }
}

extern "C" void kernel_launch(void* const* d_in, const int* in_sizes, int n_in,
                              void* d_out, int out_size, void* d_ws, size_t ws_size,
                              hipStream_t stream)
{
    const float* u   = (const float*)d_in[0];
    const float* lre = (const float*)d_in[1];
    const float* lim = (const float*)d_in[2];
    const float* B   = (const float*)d_in[3];
    const float* C   = (const float*)d_in[4];
    const float* D   = (const float*)d_in[5];
    const float* ls  = (const float*)d_in[6];
    float* out = (float*)d_out;

    char* w = (char*)d_ws;
    unsigned short* u16  = (unsigned short*)(w + 0);          // 32 MiB
    unsigned short* xs16 = (unsigned short*)(w + 33554432);   // 32 MiB
    unsigned short* Bu16 = (unsigned short*)(w + 67108864);   // 32 MiB
    unsigned short* BB   = (unsigned short*)(w + 100663296);  // 2 MiB
    unsigned short* CC   = (unsigned short*)(w + 102760448);  // 2 MiB
    float* lam   = (float*)(w + 104857600);
    float* coef  = (float*)(w + 104861696);
    float* lpow  = (float*)(w + 104865792);
    float* agg   = (float*)(w + 104869888);                   // 1 MiB
    float* xinit = (float*)(w + 105918464);                   // 1 MiB

    k_prep_lambda<<<1, P_DIM, 0, stream>>>(lre, lim, ls, lam, coef, lpow);
    k_prep_BB<<<(P_DIM*H_DIM)/256, 256, 0, stream>>>(B, coef, BB);
    k_prep_CC<<<(H_DIM*P_DIM)/256, 256, 0, stream>>>(C, CC);
    k_cast<<<(L_SEQ*H_DIM)/(256*8), 256, 0, stream>>>((const float4*)u, u16);

    gemm256<0><<<256, 512, 0, stream>>>(u16, BB, nullptr, Bu16, nullptr, nullptr);

    k_agg<<<NCHUNK, P_DIM, 0, stream>>>((const unsigned int*)Bu16, lam, agg);
    k_scan<<<P_DIM, NCHUNK, 0, stream>>>(agg, lpow, xinit);
    k_apply<<<NCHUNK, P_DIM, 0, stream>>>((const unsigned int*)Bu16, lam, xinit,
                                          (unsigned int*)xs16);

    gemm256<1><<<256, 512, 0, stream>>>(xs16, CC, out, nullptr, D, u16);
}